// Round 7
// baseline (245.889 us; speedup 1.0000x reference)
//
#include <hip/hip_runtime.h>
#include <hip/hip_fp16.h>

// ---------------------------------------------------------------------------
// DoubleAttention (A^2-Net) on MI355X.  B=16, C=512, N=4096, cm=cn=128.
// Round 6: fusion. 4 dispatches:
//   k_prep   : W->fp16 (perm'd contraction), zero gdT
//   k_abv_gd : per (nt,b): stage x fp32->fp16 in-block (transpose fused),
//              3 GEMMs (A,B,V) sharing the x tile, channel-softmax for B/V,
//              Vm -> VmT global; A,Bm -> LDS -> partial gd MFMA ->
//              atomicAdd gdT[b][k][m].  A/Bm never touch HBM.
//   k_gw     : GW[b] = WR @ gd[b]   (out = WR·(gd·Vm) = (WR·gd)·Vm)
//   k_out    : out = GW @ Vm + bR   (contraction k=128 over perm'd axis)
// Contraction-axis tensors perm'd within 32: p(k)=((k&15)>>2)*8+((k>>4)&1)*4+(k&3)
// so global_load_lds(16B) granules == MFMA fragments.
// ---------------------------------------------------------------------------

typedef _Float16 half8 __attribute__((ext_vector_type(8)));
typedef float f32x4 __attribute__((ext_vector_type(4)));

__device__ __forceinline__ unsigned short f2h(float v) {
  return __builtin_bit_cast(unsigned short, (_Float16)v);
}
__device__ __forceinline__ unsigned pk2(float a, float b) {
  return (unsigned)f2h(a) | ((unsigned)f2h(b) << 16);
}
__device__ __forceinline__ f32x4 mfma16(half8 a, half8 b, f32x4 c) {
  return __builtin_amdgcn_mfma_f32_16x16x32_f16(a, b, c, 0, 0, 0);
}
__device__ __forceinline__ int perm32(int v) {  // v in [0,32)
  return (((v & 15) >> 2) << 3) | (((v >> 4) & 1) << 2) | (v & 3);
}
__device__ __forceinline__ void glds16(const unsigned short* g, unsigned short* l) {
  __builtin_amdgcn_global_load_lds(
      (const __attribute__((address_space(1))) unsigned int*)g,
      (__attribute__((address_space(3))) unsigned int*)l, 16, 0, 0);
}
__device__ __forceinline__ half8 ld_frag(const unsigned short* lds, int row) {
  int kg = (threadIdx.x & 63) >> 4;
  uint4 u = *(const uint4*)&lds[(kg * 128 + row) * 8];
  return __builtin_bit_cast(half8, u);
}

// 256-thread stager: [128 rows][32 k(perm'd)] tile, 512 x 16B granules.
__device__ __forceinline__ void stage_glds256(unsigned short* lds,
                                              const unsigned short* g,
                                              int gs, int k0) {
  const int lane = threadIdx.x & 63;
  const int w = threadIdx.x >> 6;
#pragma unroll
  for (int p = 0; p < 2; ++p) {
    int g0 = (w + p * 4) * 64;
    int gi = g0 + lane;
    int row = gi & 127, kg = gi >> 7;
    glds16(g + (size_t)row * gs + k0 + kg * 8, lds + g0 * 8);
  }
}

// ---------------------------------------------------------------------------
__global__ __launch_bounds__(256) void k_prep(
    const float* __restrict__ WA, const float* __restrict__ WB,
    const float* __restrict__ WV, const float* __restrict__ WR,
    unsigned short* __restrict__ Wh, unsigned short* __restrict__ WRh,
    float* __restrict__ gdT) {
  int idx = blockIdx.x * 256 + threadIdx.x;  // 0..524287
  if (idx < 196608) {
    int mg = idx >> 16, r = idx & 65535;
    const float* src = (mg == 0) ? WA : ((mg == 1) ? WB : WV);
    Wh[(idx & ~31) | perm32(idx & 31)] = f2h(src[r]);
  } else if (idx < 262144) {
    int r = idx - 196608;
    WRh[(r & ~31) | perm32(r & 31)] = f2h(WR[r]);
  } else {
    gdT[idx - 262144] = 0.f;  // 16*128*128 fp32
  }
}

// ---------------------------------------------------------------------------
// grid (32 nt, 16 b), 384 threads = 6 waves. Wave w: mg = w>>1 (A/B/V),
// wh = w&1 (m-half). Per-wave output [64 m][128 n]. K=512, 16 steps, dbuf.
__global__ __launch_bounds__(384) void k_abv_gd(
    const float* __restrict__ x, const unsigned short* __restrict__ Wh,
    const float* __restrict__ bA, const float* __restrict__ bB,
    const float* __restrict__ bV,
    unsigned short* __restrict__ VmT, float* __restrict__ gdT) {
  const int nt = blockIdx.x, b = blockIdx.y;
  const int tid = threadIdx.x, lane = tid & 63, w = tid >> 6;
  const int kg = lane >> 4, lidx = lane & 15;
  const int mg = w >> 1, wh = w & 1;

  // 64 KB: phase1 = 2 x (sW 24KB + sX 8KB) dbuf; phase2 = sA2 32KB + sB2 32KB
  __shared__ unsigned short smem[32768];
  __shared__ float cmaxs[2][2][128], csums[2][2][128];
  __shared__ float sBias[384];

  sBias[tid] = ((mg == 0) ? bA : ((mg == 1) ? bB : bV))[tid & 127];

  const float* xbase = x + (size_t)b * 512 * 4096 + nt * 128;
  const int xn = tid & 127;      // granule n-row
  const int xkg = tid >> 7;      // 0..2; waves 4,5 also handle kg=3
  const bool x2 = (tid >= 256);

  float xr[16];

#define XLOAD(K0) do { \
  _Pragma("unroll") for (int j = 0; j < 4; ++j) { \
    xr[j]     = xbase[(size_t)((K0) + 4 * xkg + j) * 4096 + xn]; \
    xr[4 + j] = xbase[(size_t)((K0) + 16 + 4 * xkg + j) * 4096 + xn]; \
  } \
  if (x2) { _Pragma("unroll") for (int j = 0; j < 4; ++j) { \
    xr[8 + j]  = xbase[(size_t)((K0) + 12 + j) * 4096 + xn]; \
    xr[12 + j] = xbase[(size_t)((K0) + 28 + j) * 4096 + xn]; \
  } } } while (0)

#define XWRITE(SX) do { \
  uint4 u_; \
  u_.x = pk2(xr[0], xr[1]); u_.y = pk2(xr[2], xr[3]); \
  u_.z = pk2(xr[4], xr[5]); u_.w = pk2(xr[6], xr[7]); \
  *(uint4*)&(SX)[(xkg * 128 + xn) * 8] = u_; \
  if (x2) { \
    uint4 v_; \
    v_.x = pk2(xr[8], xr[9]);   v_.y = pk2(xr[10], xr[11]); \
    v_.z = pk2(xr[12], xr[13]); v_.w = pk2(xr[14], xr[15]); \
    *(uint4*)&(SX)[(3 * 128 + xn) * 8] = v_; \
  } } while (0)

#define WSTAGE(SW, K0) do { \
  _Pragma("unroll") for (int p = 0; p < 4; ++p) { \
    int g0_ = (w * 4 + p) * 64; \
    int gi_ = g0_ + lane; \
    int mgt_ = gi_ >> 9, q_ = gi_ & 511; \
    int kgw_ = q_ >> 7, row_ = q_ & 127; \
    glds16(Wh + mgt_ * 65536 + row_ * 512 + (K0) + kgw_ * 8, (SW) + g0_ * 8); \
  } } while (0)

  f32x4 acc[4][8];
#pragma unroll
  for (int mf = 0; mf < 4; ++mf)
#pragma unroll
    for (int nf = 0; nf < 8; ++nf) acc[mf][nf] = (f32x4){0.f, 0.f, 0.f, 0.f};

  // prologue: stage step 0 into buf 0
  XLOAD(0);
  WSTAGE(smem, 0);
  XWRITE(smem + 12288);

  for (int ks = 0; ks < 16; ++ks) {
    unsigned short* cw = smem + (ks & 1) * 16384;
    unsigned short* nx = smem + ((ks & 1) ^ 1) * 16384;
    __syncthreads();  // cur buf ready (drains glds + ds_writes)
    if (ks < 15) {
      XLOAD((ks + 1) * 32);    // global loads in flight under compute
      WSTAGE(nx, (ks + 1) * 32);
    }
    half8 af[4];
#pragma unroll
    for (int mf = 0; mf < 4; ++mf)
      af[mf] = ld_frag(cw + mg * 4096, wh * 64 + mf * 16 + lidx);
#pragma unroll
    for (int nf = 0; nf < 8; ++nf) {
      half8 bf = ld_frag(cw + 12288, nf * 16 + lidx);
#pragma unroll
      for (int mf = 0; mf < 4; ++mf)
        acc[mf][nf] = mfma16(af[mf], bf, acc[mf][nf]);
    }
    if (ks < 15) XWRITE(nx + 12288);  // convert + write next x tile
  }

  // ---- epilogue: bias ----
#pragma unroll
  for (int mf = 0; mf < 4; ++mf)
#pragma unroll
    for (int i = 0; i < 4; ++i) {
      float bb = sBias[mg * 128 + wh * 64 + mf * 16 + kg * 4 + i];
#pragma unroll
      for (int nf = 0; nf < 8; ++nf) acc[mf][nf][i] += bb;
    }

  // ---- channel softmax for mg=1,2 (over 128 m at each n) ----
  float inv_s[8];
  if (mg) {
#pragma unroll
    for (int nf = 0; nf < 8; ++nf) {
      float m = -1e30f;
#pragma unroll
      for (int mf = 0; mf < 4; ++mf)
#pragma unroll
        for (int i = 0; i < 4; ++i) m = fmaxf(m, acc[mf][nf][i]);
      m = fmaxf(m, __shfl_xor(m, 16));
      m = fmaxf(m, __shfl_xor(m, 32));
      if (kg == 0) cmaxs[mg - 1][wh][nf * 16 + lidx] = m;
      inv_s[nf] = m;  // stash local max
    }
  }
  __syncthreads();
  if (mg) {
#pragma unroll
    for (int nf = 0; nf < 8; ++nf) {
      float m = fmaxf(inv_s[nf], cmaxs[mg - 1][wh ^ 1][nf * 16 + lidx]);
      float s = 0.f;
#pragma unroll
      for (int mf = 0; mf < 4; ++mf)
#pragma unroll
        for (int i = 0; i < 4; ++i) {
          float e = __expf(acc[mf][nf][i] - m);
          acc[mf][nf][i] = e;
          s += e;
        }
      s += __shfl_xor(s, 16);
      s += __shfl_xor(s, 32);
      if (kg == 0) csums[mg - 1][wh][nf * 16 + lidx] = s;
      inv_s[nf] = s;
    }
  }
  __syncthreads();
  if (mg) {
#pragma unroll
    for (int nf = 0; nf < 8; ++nf)
      inv_s[nf] = 1.f / (inv_s[nf] + csums[mg - 1][wh ^ 1][nf * 16 + lidx]);
  }

  // ---- phase 2: A,Bm -> LDS gd-frag tiles; Vm -> global; gd MFMA ----
  unsigned short* sA2 = smem;           // [4 ks2][512 granules]
  unsigned short* sB2 = smem + 16384;

  if (mg != 2) {
    unsigned short* dst = (mg == 0) ? sA2 : sB2;
#pragma unroll
    for (int nf = 0; nf < 8; ++nf) {
      // n = nf*16+lidx -> ks2 = nf>>1, h = nf&1, kq = lidx>>2, j = lidx&3
      int base = (nf >> 1) * 4096 + (lidx >> 2) * 1024 + (nf & 1) * 4 + (lidx & 3);
#pragma unroll
      for (int mf = 0; mf < 4; ++mf)
#pragma unroll
        for (int i = 0; i < 4; ++i) {
          int m_ = wh * 64 + mf * 16 + kg * 4 + i;
          float v = acc[mf][nf][i];
          dst[base + m_ * 8] = f2h(mg ? v * inv_s[nf] : v);
        }
    }
  }
  __syncthreads();

  if (mg != 2) {
    // waves 0..3: gd GEMM, 2x2 over (gr=wh, gc=mg), contraction n=128
    const int gr = wh, gc = mg;
    f32x4 g2[4][4];
#pragma unroll
    for (int mf = 0; mf < 4; ++mf)
#pragma unroll
      for (int nf = 0; nf < 4; ++nf) g2[mf][nf] = (f32x4){0.f, 0.f, 0.f, 0.f};
#pragma unroll
    for (int ks2 = 0; ks2 < 4; ++ks2) {
      half8 af2[4];
#pragma unroll
      for (int mf = 0; mf < 4; ++mf)
        af2[mf] = ld_frag(sA2 + ks2 * 4096, gr * 64 + mf * 16 + lidx);
#pragma unroll
      for (int nf = 0; nf < 4; ++nf) {
        half8 bf2 = ld_frag(sB2 + ks2 * 4096, gc * 64 + nf * 16 + lidx);
#pragma unroll
        for (int mf = 0; mf < 4; ++mf)
          g2[mf][nf] = mfma16(af2[mf], bf2, g2[mf][nf]);
      }
    }
    float* gb = gdT + (size_t)b * 16384;  // gdT[b][k][m]
#pragma unroll
    for (int mf = 0; mf < 4; ++mf)
#pragma unroll
      for (int nf = 0; nf < 4; ++nf)
#pragma unroll
        for (int i = 0; i < 4; ++i) {
          int m_ = gr * 64 + mf * 16 + kg * 4 + i;
          int k2 = gc * 64 + nf * 16 + lidx;
          atomicAdd(&gb[k2 * 128 + m_], g2[mf][nf][i]);
        }
  } else {
    // waves 4,5: Vm -> VmT[b][n][k'] (overlaps gd GEMM)
    const size_t vofs = ((size_t)b * 4096 + (size_t)nt * 128) * 128;
#pragma unroll
    for (int mf = 0; mf < 4; ++mf) {
      int m0 = wh * 64 + mf * 16 + kg * 4;
      int mp = (m0 & ~31) + perm32(m0 & 31);
#pragma unroll
      for (int nf = 0; nf < 8; ++nf) {
        int n_ = nf * 16 + lidx;
        ushort4 pk;
        pk.x = f2h(acc[mf][nf][0] * inv_s[nf]);
        pk.y = f2h(acc[mf][nf][1] * inv_s[nf]);
        pk.z = f2h(acc[mf][nf][2] * inv_s[nf]);
        pk.w = f2h(acc[mf][nf][3] * inv_s[nf]);
        *(ushort4*)&VmT[vofs + (size_t)n_ * 128 + mp] = pk;
      }
    }
  }
#undef XLOAD
#undef XWRITE
#undef WSTAGE
}

// ---------------------------------------------------------------------------
// GW[b] = WR @ gd[b]:  D[k-rows][c-cols], A = gdT[k][m] (reg-staged fp32->fp16),
// B = WRh[c][m'] (glds). Write GWh[b][c][k'] as ushort4 (perm-contig in i).
// grid (4 ct, 16 b)
__global__ __launch_bounds__(256) void k_gw(
    const float* __restrict__ gdT, const unsigned short* __restrict__ WRh,
    unsigned short* __restrict__ GWh) {
  const int ct = blockIdx.x, b = blockIdx.y;
  const int tid = threadIdx.x, lane = tid & 63;
  const int w = tid >> 6, wr = w >> 1, wc = w & 1;
  const int kg = lane >> 4, lidx = lane & 15;
  __shared__ unsigned short sG[4096], sWr[4096];
  const float* gb = gdT + (size_t)b * 16384;
  const unsigned short* Wb = WRh + ct * 128 * 128;

  f32x4 acc[4][4];
#pragma unroll
  for (int mf = 0; mf < 4; ++mf)
#pragma unroll
    for (int nf = 0; nf < 4; ++nf) acc[mf][nf] = (f32x4){0.f, 0.f, 0.f, 0.f};

  for (int k0 = 0; k0 < 128; k0 += 32) {
#pragma unroll
    for (int p = 0; p < 2; ++p) {
      int g = tid + p * 256;
      int row = g & 127, kgx = g >> 7;
      const float* s0 = &gb[row * 128 + k0 + 4 * kgx];
      float4 v0 = *(const float4*)s0;
      float4 v1 = *(const float4*)(s0 + 16);
      uint4 u;
      u.x = pk2(v0.x, v0.y); u.y = pk2(v0.z, v0.w);
      u.z = pk2(v1.x, v1.y); u.w = pk2(v1.z, v1.w);
      *(uint4*)&sG[g * 8] = u;
    }
    stage_glds256(sWr, Wb, 128, k0);
    __syncthreads();
    half8 af[4];
#pragma unroll
    for (int mf = 0; mf < 4; ++mf) af[mf] = ld_frag(sG, wr * 64 + mf * 16 + lidx);
#pragma unroll
    for (int nf = 0; nf < 4; ++nf) {
      half8 bf = ld_frag(sWr, wc * 64 + nf * 16 + lidx);
#pragma unroll
      for (int mf = 0; mf < 4; ++mf) acc[mf][nf] = mfma16(af[mf], bf, acc[mf][nf]);
    }
    __syncthreads();
  }
  const size_t gofs = ((size_t)b * 512 + (size_t)ct * 128) * 128;
#pragma unroll
  for (int mf = 0; mf < 4; ++mf) {
    int k0g = wr * 64 + mf * 16 + kg * 4;
    int kp = (k0g & ~31) + perm32(k0g & 31);  // perm consecutive over i
#pragma unroll
    for (int nf = 0; nf < 4; ++nf) {
      int c_ = wc * 64 + nf * 16 + lidx;
      ushort4 pk;
      pk.x = f2h(acc[mf][nf][0]); pk.y = f2h(acc[mf][nf][1]);
      pk.z = f2h(acc[mf][nf][2]); pk.w = f2h(acc[mf][nf][3]);
      *(ushort4*)&GWh[gofs + (size_t)c_ * 128 + kp] = pk;
    }
  }
}

// ---------------------------------------------------------------------------
// out[b][c][n] = sum_k GW[b][c][k'] VmT[b][n][k'] + bR[c]; grid (32 nt, 4 ct, 16 b)
__global__ __launch_bounds__(256) void k_out(
    const unsigned short* __restrict__ GWh, const unsigned short* __restrict__ VmT,
    const float* __restrict__ bR, float* __restrict__ out) {
  const int nt = blockIdx.x, ct = blockIdx.y, b = blockIdx.z;
  const int tid = threadIdx.x, lane = tid & 63;
  const int w = tid >> 6, wr = w >> 1, wc = w & 1;
  const int kg = lane >> 4, lidx = lane & 15;
  __shared__ unsigned short sW[4096], sZ[4096];
  __shared__ float sBias[128];
  if (tid < 128) sBias[tid] = bR[ct * 128 + tid];
  const unsigned short* Wb = GWh + ((size_t)b * 512 + (size_t)ct * 128) * 128;
  const unsigned short* Zb = VmT + ((size_t)b * 4096 + (size_t)nt * 128) * 128;

  f32x4 acc[4][4];
#pragma unroll
  for (int mf = 0; mf < 4; ++mf)
#pragma unroll
    for (int nf = 0; nf < 4; ++nf) acc[mf][nf] = (f32x4){0.f, 0.f, 0.f, 0.f};

  for (int k0 = 0; k0 < 128; k0 += 32) {
    stage_glds256(sW, Wb, 128, k0);
    stage_glds256(sZ, Zb, 128, k0);
    __syncthreads();
    half8 af[4];
#pragma unroll
    for (int mf = 0; mf < 4; ++mf) af[mf] = ld_frag(sW, wr * 64 + mf * 16 + lidx);
#pragma unroll
    for (int nf = 0; nf < 4; ++nf) {
      half8 bf = ld_frag(sZ, wc * 64 + nf * 16 + lidx);
#pragma unroll
      for (int mf = 0; mf < 4; ++mf) acc[mf][nf] = mfma16(af[mf], bf, acc[mf][nf]);
    }
    __syncthreads();
  }
#pragma unroll
  for (int mf = 0; mf < 4; ++mf)
#pragma unroll
    for (int nf = 0; nf < 4; ++nf)
#pragma unroll
      for (int i = 0; i < 4; ++i) {
        int cl = wr * 64 + mf * 16 + kg * 4 + i;
        int n_ = nt * 128 + wc * 64 + nf * 16 + lidx;
        out[((size_t)b * 512 + ct * 128 + cl) * 4096 + n_] = acc[mf][nf][i] + sBias[cl];
      }
}

// ---------------------------------------------------------------------------
extern "C" void kernel_launch(void* const* d_in, const int* in_sizes, int n_in,
                              void* d_out, int out_size, void* d_ws, size_t ws_size,
                              hipStream_t stream) {
  const float* x  = (const float*)d_in[0];
  const float* WA = (const float*)d_in[1];
  const float* bA = (const float*)d_in[2];
  const float* WB = (const float*)d_in[3];
  const float* bB = (const float*)d_in[4];
  const float* WV = (const float*)d_in[5];
  const float* bV = (const float*)d_in[6];
  const float* WR = (const float*)d_in[7];
  const float* bR = (const float*)d_in[8];
  float* out = (float*)d_out;

  char* ws = (char*)d_ws;
  unsigned short* Wh  = (unsigned short*)(ws);              // 3*128*512 fp16
  unsigned short* WRh = (unsigned short*)(ws + 393216);     // 512*128 fp16
  unsigned short* VmT = (unsigned short*)(ws + 524288);     // 16*4096*128 fp16
  float*          gdT = (float*)(ws + 17301504);            // 16*128*128 fp32
  unsigned short* GWh = (unsigned short*)(ws + 18350080);   // 16*512*128 fp16

  k_prep<<<2048, 256, 0, stream>>>(WA, WB, WV, WR, Wh, WRh, gdT);
  k_abv_gd<<<dim3(32, 16), 384, 0, stream>>>(x, Wh, bA, bB, bV, VmT, gdT);
  k_gw<<<dim3(4, 16), 256, 0, stream>>>(gdT, WRh, GWh);
  k_out<<<dim3(32, 4, 16), 256, 0, stream>>>(GWh, VmT, bR, out);
}

// Round 8
// 152.798 us; speedup vs baseline: 1.6092x; 1.6092x over previous
//
#include <hip/hip_runtime.h>
#include <hip/hip_fp16.h>

// ---------------------------------------------------------------------------
// DoubleAttention (A^2-Net) on MI355X.  B=16, C=512, N=4096, cm=cn=128.
// Round 7: R6 fusion, de-serialized.
//   k_prep   : W->fp16 (perm'd contraction axis)
//   k_abv_gd : per (nt,b): x staged in-block (transpose+cvt fused, dbuf),
//              W fragments loaded global->reg (L2-resident, prefetched),
//              3 GEMMs (A,B,V) + channel softmax; Vm->VmT global;
//              A,Bm -> LDS (two 64-n rounds) -> gd MFMA ->
//              PLAIN float4 stores of per-block partials gdP (no atomics).
//   k_gdred  : gdT[b][k][m] = sum_nt gdP[b][nt][k][m]
//   k_gw     : GW[b] = WR @ gd[b]    (out = (WR*gd)*Vm)
//   k_out    : out = GW @ Vm + bR
// Contraction-axis tensors perm'd within 32: p(k)=((k&15)>>2)*8+((k>>4)&1)*4+(k&3)
// so 16B global chunks == MFMA fragments (LDS granule (kg*128+row)*8 halves).
// ---------------------------------------------------------------------------

typedef _Float16 half8 __attribute__((ext_vector_type(8)));
typedef float f32x4 __attribute__((ext_vector_type(4)));

__device__ __forceinline__ unsigned short f2h(float v) {
  return __builtin_bit_cast(unsigned short, (_Float16)v);
}
__device__ __forceinline__ unsigned pk2(float a, float b) {
  return (unsigned)f2h(a) | ((unsigned)f2h(b) << 16);
}
__device__ __forceinline__ f32x4 mfma16(half8 a, half8 b, f32x4 c) {
  return __builtin_amdgcn_mfma_f32_16x16x32_f16(a, b, c, 0, 0, 0);
}
__device__ __forceinline__ int perm32(int v) {  // v in [0,32)
  return (((v & 15) >> 2) << 3) | (((v >> 4) & 1) << 2) | (v & 3);
}
__device__ __forceinline__ void glds16(const unsigned short* g, unsigned short* l) {
  __builtin_amdgcn_global_load_lds(
      (const __attribute__((address_space(1))) unsigned int*)g,
      (__attribute__((address_space(3))) unsigned int*)l, 16, 0, 0);
}
__device__ __forceinline__ half8 ld_frag(const unsigned short* lds, int row) {
  int kg = (threadIdx.x & 63) >> 4;
  uint4 u = *(const uint4*)&lds[(kg * 128 + row) * 8];
  return __builtin_bit_cast(half8, u);
}

// 256-thread stager: [128 rows][32 k(perm'd)] tile, 512 x 16B granules.
__device__ __forceinline__ void stage_glds256(unsigned short* lds,
                                              const unsigned short* g,
                                              int gs, int k0) {
  const int lane = threadIdx.x & 63;
  const int w = threadIdx.x >> 6;
#pragma unroll
  for (int p = 0; p < 2; ++p) {
    int g0 = (w + p * 4) * 64;
    int gi = g0 + lane;
    int row = gi & 127, kg = gi >> 7;
    glds16(g + (size_t)row * gs + k0 + kg * 8, lds + g0 * 8);
  }
}

// ---------------------------------------------------------------------------
__global__ __launch_bounds__(256) void k_prep(
    const float* __restrict__ WA, const float* __restrict__ WB,
    const float* __restrict__ WV, const float* __restrict__ WR,
    unsigned short* __restrict__ Wh, unsigned short* __restrict__ WRh) {
  int idx = blockIdx.x * 256 + threadIdx.x;  // 0..262143
  if (idx < 196608) {
    int mg = idx >> 16, r = idx & 65535;
    const float* src = (mg == 0) ? WA : ((mg == 1) ? WB : WV);
    Wh[(idx & ~31) | perm32(idx & 31)] = f2h(src[r]);
  } else {
    int r = idx - 196608;
    WRh[(r & ~31) | perm32(r & 31)] = f2h(WR[r]);
  }
}

// ---------------------------------------------------------------------------
// grid (32 nt, 16 b), 384 threads = 6 waves. Wave w: mg = w>>1 (A/B/V),
// wh = w&1 (m-half). Per-wave output [64 m][128 n]. K=512, 16 steps.
// LDS: smem 32KB = phase1 x-dbuf (2 x 8KB) / phase2 sA2+sB2 (2 x 16KB).
__global__ __launch_bounds__(384) void k_abv_gd(
    const float* __restrict__ x, const unsigned short* __restrict__ Wh,
    const float* __restrict__ bA, const float* __restrict__ bB,
    const float* __restrict__ bV,
    unsigned short* __restrict__ VmT, float* __restrict__ gdP) {
  const int nt = blockIdx.x, b = blockIdx.y;
  const int tid = threadIdx.x, lane = tid & 63, w = tid >> 6;
  const int kg = lane >> 4, lidx = lane & 15;
  const int mg = w >> 1, wh = w & 1;

  __shared__ unsigned short smem[16384];            // 32 KB
  __shared__ float cmaxs[2][2][128], csums[2][2][128];
  __shared__ float sBias[384];

  sBias[tid] = ((mg == 0) ? bA : ((mg == 1) ? bB : bV))[tid & 127];

  const float* xbase = x + (size_t)b * 512 * 4096 + nt * 128;
  const int xn = tid & 127;      // granule n-row
  const int xkg = tid >> 7;      // 0..2; threads >=256 also do kg=3
  const bool x2 = (tid >= 256);

  float xr[16];

#define XLOAD(K0) do { \
  _Pragma("unroll") for (int j = 0; j < 4; ++j) { \
    xr[j]     = xbase[(size_t)((K0) + 4 * xkg + j) * 4096 + xn]; \
    xr[4 + j] = xbase[(size_t)((K0) + 16 + 4 * xkg + j) * 4096 + xn]; \
  } \
  if (x2) { _Pragma("unroll") for (int j = 0; j < 4; ++j) { \
    xr[8 + j]  = xbase[(size_t)((K0) + 12 + j) * 4096 + xn]; \
    xr[12 + j] = xbase[(size_t)((K0) + 28 + j) * 4096 + xn]; \
  } } } while (0)

#define XWRITE(SX) do { \
  uint4 u_; \
  u_.x = pk2(xr[0], xr[1]); u_.y = pk2(xr[2], xr[3]); \
  u_.z = pk2(xr[4], xr[5]); u_.w = pk2(xr[6], xr[7]); \
  *(uint4*)&(SX)[(xkg * 128 + xn) * 8] = u_; \
  if (x2) { \
    uint4 v_; \
    v_.x = pk2(xr[8], xr[9]);   v_.y = pk2(xr[10], xr[11]); \
    v_.z = pk2(xr[12], xr[13]); v_.w = pk2(xr[14], xr[15]); \
    *(uint4*)&(SX)[(3 * 128 + xn) * 8] = v_; \
  } } while (0)

  // W fragments: direct global->reg, 16B per lane, L2-resident.
#define WLOAD(AF, K0) do { \
  _Pragma("unroll") for (int mf_ = 0; mf_ < 4; ++mf_) { \
    const unsigned short* wp_ = Wh + mg * 65536 + \
        (size_t)(wh * 64 + mf_ * 16 + lidx) * 512 + (K0) + kg * 8; \
    (AF)[mf_] = __builtin_bit_cast(half8, *(const uint4*)wp_); \
  } } while (0)

  f32x4 acc[4][8];
#pragma unroll
  for (int mf = 0; mf < 4; ++mf)
#pragma unroll
    for (int nf = 0; nf < 8; ++nf) acc[mf][nf] = (f32x4){0.f, 0.f, 0.f, 0.f};

  half8 afc[4], afn[4];

  // prologue: step 0
  XLOAD(0);
  WLOAD(afc, 0);
  XWRITE(smem);

  for (int ks = 0; ks < 16; ++ks) {
    unsigned short* cw = smem + (ks & 1) * 4096;
    unsigned short* nx = smem + ((ks & 1) ^ 1) * 4096;
    __syncthreads();  // current x buf ready
    if (ks < 15) {
      XLOAD((ks + 1) * 32);   // global loads in flight under compute
      WLOAD(afn, (ks + 1) * 32);
    }
#pragma unroll
    for (int nf = 0; nf < 8; ++nf) {
      half8 bf = ld_frag(cw, nf * 16 + lidx);
#pragma unroll
      for (int mf = 0; mf < 4; ++mf)
        acc[mf][nf] = mfma16(afc[mf], bf, acc[mf][nf]);
    }
    if (ks < 15) {
      XWRITE(nx);
#pragma unroll
      for (int mf = 0; mf < 4; ++mf) afc[mf] = afn[mf];
    }
  }

  // ---- bias ----
#pragma unroll
  for (int mf = 0; mf < 4; ++mf)
#pragma unroll
    for (int i = 0; i < 4; ++i) {
      float bb = sBias[mg * 128 + wh * 64 + mf * 16 + kg * 4 + i];
#pragma unroll
      for (int nf = 0; nf < 8; ++nf) acc[mf][nf][i] += bb;
    }

  // ---- channel softmax for mg=1,2 (over 128 m at each n) ----
  float inv_s[8];
  if (mg) {
#pragma unroll
    for (int nf = 0; nf < 8; ++nf) {
      float m = -1e30f;
#pragma unroll
      for (int mf = 0; mf < 4; ++mf)
#pragma unroll
        for (int i = 0; i < 4; ++i) m = fmaxf(m, acc[mf][nf][i]);
      m = fmaxf(m, __shfl_xor(m, 16));
      m = fmaxf(m, __shfl_xor(m, 32));
      if (kg == 0) cmaxs[mg - 1][wh][nf * 16 + lidx] = m;
      inv_s[nf] = m;
    }
  }
  __syncthreads();
  if (mg) {
#pragma unroll
    for (int nf = 0; nf < 8; ++nf) {
      float m = fmaxf(inv_s[nf], cmaxs[mg - 1][wh ^ 1][nf * 16 + lidx]);
      float s = 0.f;
#pragma unroll
      for (int mf = 0; mf < 4; ++mf)
#pragma unroll
        for (int i = 0; i < 4; ++i) {
          float e = __expf(acc[mf][nf][i] - m);
          acc[mf][nf][i] = e;
          s += e;
        }
      s += __shfl_xor(s, 16);
      s += __shfl_xor(s, 32);
      if (kg == 0) csums[mg - 1][wh][nf * 16 + lidx] = s;
      inv_s[nf] = s;
    }
  }
  __syncthreads();
  if (mg) {
#pragma unroll
    for (int nf = 0; nf < 8; ++nf)
      inv_s[nf] = 1.f / (inv_s[nf] + csums[mg - 1][wh ^ 1][nf * 16 + lidx]);
  }

  // ---- Vm -> global (waves mg==2), overlaps the gd rounds below ----
  if (mg == 2) {
    const size_t vofs = ((size_t)b * 4096 + (size_t)nt * 128) * 128;
#pragma unroll
    for (int mf = 0; mf < 4; ++mf) {
      int m0 = wh * 64 + mf * 16 + kg * 4;
      int mp = (m0 & ~31) + perm32(m0 & 31);
#pragma unroll
      for (int nf = 0; nf < 8; ++nf) {
        int n_ = nf * 16 + lidx;
        ushort4 pk;
        pk.x = f2h(acc[mf][nf][0] * inv_s[nf]);
        pk.y = f2h(acc[mf][nf][1] * inv_s[nf]);
        pk.z = f2h(acc[mf][nf][2] * inv_s[nf]);
        pk.w = f2h(acc[mf][nf][3] * inv_s[nf]);
        *(ushort4*)&VmT[vofs + (size_t)n_ * 128 + mp] = pk;
      }
    }
  }

  // ---- phase 2: gd = A (.) Bm over n=128, two 64-n rounds in 32KB LDS ----
  unsigned short* sA2 = smem;          // [2 ks2][4096 halves]
  unsigned short* sB2 = smem + 8192;
  const int gr = wh, gc = mg;          // quadrant for waves mg in {0,1}

  f32x4 g2[4][4];
#pragma unroll
  for (int mf = 0; mf < 4; ++mf)
#pragma unroll
    for (int nf = 0; nf < 4; ++nf) g2[mf][nf] = (f32x4){0.f, 0.f, 0.f, 0.f};

#pragma unroll
  for (int r = 0; r < 2; ++r) {
    __syncthreads();  // r0: phase-1/softmax LDS reads done; r1: round-0 MFMA done
    if (mg != 2) {
      unsigned short* dst = (mg == 0) ? sA2 : sB2;
#pragma unroll
      for (int nfl = 0; nfl < 4; ++nfl) {
        int nf = r * 4 + nfl;
        int base = (nfl >> 1) * 4096 + (lidx >> 2) * 1024 + (nf & 1) * 4 + (lidx & 3);
#pragma unroll
        for (int mf = 0; mf < 4; ++mf)
#pragma unroll
          for (int i = 0; i < 4; ++i) {
            int m_ = wh * 64 + mf * 16 + kg * 4 + i;
            float v = acc[mf][nf][i];
            dst[base + m_ * 8] = f2h(mg ? v * inv_s[nf] : v);
          }
      }
    }
    __syncthreads();
    if (mg != 2) {
#pragma unroll
      for (int ks2 = 0; ks2 < 2; ++ks2) {
        half8 af2[4];
#pragma unroll
        for (int mf = 0; mf < 4; ++mf)
          af2[mf] = ld_frag(sA2 + ks2 * 4096, gr * 64 + mf * 16 + lidx);
#pragma unroll
        for (int nf = 0; nf < 4; ++nf) {
          half8 bf2 = ld_frag(sB2 + ks2 * 4096, gc * 64 + nf * 16 + lidx);
#pragma unroll
          for (int mf = 0; mf < 4; ++mf)
            g2[mf][nf] = mfma16(af2[mf], bf2, g2[mf][nf]);
        }
      }
    }
  }

  if (mg != 2) {  // plain stores of per-block partial: gdP[b][nt][k][m]
    float* gp = gdP + ((size_t)b * 32 + nt) * 16384;
#pragma unroll
    for (int mf = 0; mf < 4; ++mf)
#pragma unroll
      for (int nf = 0; nf < 4; ++nf) {
        int m0 = gr * 64 + mf * 16 + kg * 4;
        int k2 = gc * 64 + nf * 16 + lidx;
        *(f32x4*)&gp[(size_t)k2 * 128 + m0] = g2[mf][nf];
      }
  }
#undef XLOAD
#undef XWRITE
#undef WLOAD
}

// ---------------------------------------------------------------------------
// gdT[b][k][m] = sum_nt gdP[b][nt][k][m];  grid 256 x 256 thr, float4/thread
__global__ __launch_bounds__(256) void k_gdred(
    const float* __restrict__ gdP, float* __restrict__ gdT) {
  int gid = blockIdx.x * 256 + threadIdx.x;  // 0..65535
  int o = gid * 4;
  int b = o >> 14, rem = o & 16383;
  const float* src = gdP + (size_t)b * 32 * 16384 + rem;
  f32x4 s = (f32x4){0.f, 0.f, 0.f, 0.f};
#pragma unroll 8
  for (int nt = 0; nt < 32; ++nt) s += *(const f32x4*)(src + (size_t)nt * 16384);
  *(f32x4*)(gdT + o) = s;
}

// ---------------------------------------------------------------------------
// GW[b] = WR @ gd[b]: A = gdT[k][m] (reg-staged fp32->fp16), B = WRh[c][m'].
// Writes GWh[b][c][k'] (k perm'd). grid (4 ct, 16 b)
__global__ __launch_bounds__(256) void k_gw(
    const float* __restrict__ gdT, const unsigned short* __restrict__ WRh,
    unsigned short* __restrict__ GWh) {
  const int ct = blockIdx.x, b = blockIdx.y;
  const int tid = threadIdx.x, lane = tid & 63;
  const int w = tid >> 6, wr = w >> 1, wc = w & 1;
  const int kg = lane >> 4, lidx = lane & 15;
  __shared__ unsigned short sG[4096], sWr[4096];
  const float* gb = gdT + (size_t)b * 16384;
  const unsigned short* Wb = WRh + ct * 128 * 128;

  f32x4 acc[4][4];
#pragma unroll
  for (int mf = 0; mf < 4; ++mf)
#pragma unroll
    for (int nf = 0; nf < 4; ++nf) acc[mf][nf] = (f32x4){0.f, 0.f, 0.f, 0.f};

  for (int k0 = 0; k0 < 128; k0 += 32) {
#pragma unroll
    for (int p = 0; p < 2; ++p) {
      int g = tid + p * 256;
      int row = g & 127, kgx = g >> 7;
      const float* s0 = &gb[row * 128 + k0 + 4 * kgx];
      float4 v0 = *(const float4*)s0;
      float4 v1 = *(const float4*)(s0 + 16);
      uint4 u;
      u.x = pk2(v0.x, v0.y); u.y = pk2(v0.z, v0.w);
      u.z = pk2(v1.x, v1.y); u.w = pk2(v1.z, v1.w);
      *(uint4*)&sG[g * 8] = u;
    }
    stage_glds256(sWr, Wb, 128, k0);
    __syncthreads();
    half8 af[4];
#pragma unroll
    for (int mf = 0; mf < 4; ++mf) af[mf] = ld_frag(sG, wr * 64 + mf * 16 + lidx);
#pragma unroll
    for (int nf = 0; nf < 4; ++nf) {
      half8 bf = ld_frag(sWr, wc * 64 + nf * 16 + lidx);
#pragma unroll
      for (int mf = 0; mf < 4; ++mf) acc[mf][nf] = mfma16(af[mf], bf, acc[mf][nf]);
    }
    __syncthreads();
  }
  const size_t gofs = ((size_t)b * 512 + (size_t)ct * 128) * 128;
#pragma unroll
  for (int mf = 0; mf < 4; ++mf) {
    int k0g = wr * 64 + mf * 16 + kg * 4;
    int kp = (k0g & ~31) + perm32(k0g & 31);
#pragma unroll
    for (int nf = 0; nf < 4; ++nf) {
      int c_ = wc * 64 + nf * 16 + lidx;
      ushort4 pk;
      pk.x = f2h(acc[mf][nf][0]); pk.y = f2h(acc[mf][nf][1]);
      pk.z = f2h(acc[mf][nf][2]); pk.w = f2h(acc[mf][nf][3]);
      *(ushort4*)&GWh[gofs + (size_t)c_ * 128 + kp] = pk;
    }
  }
}

// ---------------------------------------------------------------------------
// out[b][c][n] = sum_k GW[b][c][k'] VmT[b][n][k'] + bR[c]; grid (32,4,16)
__global__ __launch_bounds__(256) void k_out(
    const unsigned short* __restrict__ GWh, const unsigned short* __restrict__ VmT,
    const float* __restrict__ bR, float* __restrict__ out) {
  const int nt = blockIdx.x, ct = blockIdx.y, b = blockIdx.z;
  const int tid = threadIdx.x, lane = tid & 63;
  const int w = tid >> 6, wr = w >> 1, wc = w & 1;
  const int kg = lane >> 4, lidx = lane & 15;
  __shared__ unsigned short sW[4096], sZ[4096];
  __shared__ float sBias[128];
  if (tid < 128) sBias[tid] = bR[ct * 128 + tid];
  const unsigned short* Wb = GWh + ((size_t)b * 512 + (size_t)ct * 128) * 128;
  const unsigned short* Zb = VmT + ((size_t)b * 4096 + (size_t)nt * 128) * 128;

  f32x4 acc[4][4];
#pragma unroll
  for (int mf = 0; mf < 4; ++mf)
#pragma unroll
    for (int nf = 0; nf < 4; ++nf) acc[mf][nf] = (f32x4){0.f, 0.f, 0.f, 0.f};

  for (int k0 = 0; k0 < 128; k0 += 32) {
    stage_glds256(sW, Wb, 128, k0);
    stage_glds256(sZ, Zb, 128, k0);
    __syncthreads();
    half8 af[4];
#pragma unroll
    for (int mf = 0; mf < 4; ++mf) af[mf] = ld_frag(sW, wr * 64 + mf * 16 + lidx);
#pragma unroll
    for (int nf = 0; nf < 4; ++nf) {
      half8 bf = ld_frag(sZ, wc * 64 + nf * 16 + lidx);
#pragma unroll
      for (int mf = 0; mf < 4; ++mf) acc[mf][nf] = mfma16(af[mf], bf, acc[mf][nf]);
    }
    __syncthreads();
  }
#pragma unroll
  for (int mf = 0; mf < 4; ++mf)
#pragma unroll
    for (int nf = 0; nf < 4; ++nf)
#pragma unroll
      for (int i = 0; i < 4; ++i) {
        int cl = wr * 64 + mf * 16 + kg * 4 + i;
        int n_ = nt * 128 + wc * 64 + nf * 16 + lidx;
        out[((size_t)b * 512 + ct * 128 + cl) * 4096 + n_] = acc[mf][nf][i] + sBias[cl];
      }
}

// ---------------------------------------------------------------------------
extern "C" void kernel_launch(void* const* d_in, const int* in_sizes, int n_in,
                              void* d_out, int out_size, void* d_ws, size_t ws_size,
                              hipStream_t stream) {
  const float* x  = (const float*)d_in[0];
  const float* WA = (const float*)d_in[1];
  const float* bA = (const float*)d_in[2];
  const float* WB = (const float*)d_in[3];
  const float* bB = (const float*)d_in[4];
  const float* WV = (const float*)d_in[5];
  const float* bV = (const float*)d_in[6];
  const float* WR = (const float*)d_in[7];
  const float* bR = (const float*)d_in[8];
  float* out = (float*)d_out;

  char* ws = (char*)d_ws;
  unsigned short* Wh  = (unsigned short*)(ws);              // 3*128*512 fp16
  unsigned short* WRh = (unsigned short*)(ws + 393216);     // 512*128 fp16
  unsigned short* VmT = (unsigned short*)(ws + 524288);     // 16*4096*128 fp16
  float*          gdT = (float*)(ws + 17301504);            // 16*128*128 fp32
  unsigned short* GWh = (unsigned short*)(ws + 18350080);   // 16*512*128 fp16
  float*          gdP = (float*)(ws + 20447232);            // 16*32*128*128 fp32 (32MB)

  k_prep<<<1024, 256, 0, stream>>>(WA, WB, WV, WR, Wh, WRh);
  k_abv_gd<<<dim3(32, 16), 384, 0, stream>>>(x, Wh, bA, bB, bV, VmT, gdP);
  k_gdred<<<256, 256, 0, stream>>>(gdP, gdT);
  k_gw<<<dim3(4, 16), 256, 0, stream>>>(gdT, WRh, GWh);
  k_out<<<dim3(32, 4, 16), 256, 0, stream>>>(GWh, VmT, bR, out);
}